// Round 14
// baseline (503.444 us; speedup 1.0000x reference)
//
#include <hip/hip_runtime.h>

typedef unsigned short u16;
typedef unsigned int u32;
typedef __attribute__((ext_vector_type(8))) short short8;
typedef __attribute__((ext_vector_type(4))) float floatx4;

#define LN_EPS 1e-5f

__device__ __forceinline__ float bf2f(u16 u) {
    union { u32 i; float f; } v; v.i = ((u32)u) << 16; return v.f;
}
__device__ __forceinline__ u16 f2bf(float f) {
    union { u32 i; float f; } v; v.f = f;
    u32 x = v.i;
    return (u16)((x + 0x7fffu + ((x >> 16) & 1u)) >> 16);
}
__device__ __forceinline__ int clampi(int v, int lo, int hi) {
    return v < lo ? lo : (v > hi ? hi : v);
}

// Async 16B global->LDS DMA (no VGPR round-trip). LDS dest must be
// wave-uniform base + lane*16 — our staging pattern satisfies this.
__device__ __forceinline__ void g2lds16(const void* g, void* l) {
    __builtin_amdgcn_global_load_lds(
        (__attribute__((address_space(1))) const u32*)g,
        (__attribute__((address_space(3))) u32*)l, 16, 0, 0);
}

// Diagnostic fill (f32) — error paths only.
__global__ void k_fill(float* __restrict__ out, int nel, float val) {
    int i = blockIdx.x * blockDim.x + threadIdx.x;
    if (i < nel) out[i] = val;
}

// ---------------- preprocessing ----------------
// pre0 = detect + deg-zero + weight swizzle (all disjoint work, union grid).
// NOTE (R12 lesson): cooperative grid.sync costs ~70 µs/sync on MI355X
// (cross-XCD L2 flush); stream-ordered separate kernels are 15x cheaper.
__global__ void k_pre0(const int* __restrict__ ei, int E, int* __restrict__ flag,
                       int* __restrict__ deg, int n,
                       const float* __restrict__ W1, const float* __restrict__ W2,
                       const float* __restrict__ Wr, const float* __restrict__ nW,
                       u16* __restrict__ W1s, u16* __restrict__ W2s,
                       u16* __restrict__ Wrs, u16* __restrict__ nWs) {
    int t = threadIdx.x;
    if (blockIdx.x == 0) {
        __shared__ int any;
        if (t == 0) any = 0;
        __syncthreads();
        int lim = (E < 4096) ? E : 4096;
        int v = 0;
        for (int i = t; i < lim; i += 256) v |= ei[2 * i + 1];
        if (v) atomicOr(&any, 1);
        __syncthreads();
        if (t == 0) flag[0] = (any == 0) ? 1 : 0;
    }
    int i = blockIdx.x * 256 + t;
    if (i < n) deg[i] = 0;
    // weight swizzle into MFMA B-frag order: k = kt*32+q*8+j -> ((kt*4+q)*N+n)*8+j
    if (i < 3 * 24576) {
        int l = i / 24576, rem = i % 24576;
        int k = rem / 128, c = rem % 128;
        int kt = k >> 5, q = (k >> 3) & 3, j = k & 7;
        W1s[l * 24576 + ((kt * 4 + q) * 128 + c) * 8 + j] = f2bf(W1[i]);
    }
    if (i < 3 * 8192) {
        int l = i / 8192, rem = i % 8192;
        int k = rem / 64, c = rem % 64;
        int kt = k >> 5, q = (k >> 3) & 3, j = k & 7;
        W2s[l * 8192 + ((kt * 4 + q) * 64 + c) * 8 + j] = f2bf(W2[i]);
    }
    if (i < 3 * 4096) {
        int l = i / 4096, rem = i % 4096;
        int k = rem / 64, c = rem % 64;
        int kt = k >> 5, q = (k >> 3) & 3, j = k & 7;
        Wrs[l * 4096 + ((kt * 4 + q) * 64 + c) * 8 + j] = f2bf(Wr[i]);
    }
    if (i < 8192) {
        int k = i / 64, c = i % 64;
        int kt = k >> 5, q = (k >> 3) & 3, j = k & 7;
        nWs[((kt * 4 + q) * 64 + c) * 8 + j] = f2bf(nW[i]);
    }
}

__global__ void k_hist(const int* __restrict__ ei, const int* __restrict__ flag,
                       int* __restrict__ deg, int E, int n) {
    int e = blockIdx.x * blockDim.x + threadIdx.x;
    if (e < E) {
        int d = flag[0] ? ei[2 * ((size_t)E + e)] : ei[(size_t)E + e];
        atomicAdd(&deg[clampi(d, 0, n - 1)], 1);
    }
}

__global__ void k_scan1(const int* __restrict__ deg, int* __restrict__ offs,
                        int* __restrict__ bsum, int n) {
    __shared__ int s[256];
    int t = threadIdx.x;
    int i = blockIdx.x * 256 + t;
    int v = (i < n) ? deg[i] : 0;
    s[t] = v; __syncthreads();
    for (int off = 1; off < 256; off <<= 1) {
        int x = (t >= off) ? s[t - off] : 0;
        __syncthreads();
        s[t] += x;
        __syncthreads();
    }
    if (i < n) offs[i] = s[t] - v;
    if (t == 255) bsum[blockIdx.x] = s[255];
}

// scan2+scan3 merged — every block redundantly scans bsum (nb <= 256) in LDS
// and applies its own exclusive block offset.
__global__ void k_scan23(int* __restrict__ offs, const int* __restrict__ bsum,
                         int* __restrict__ cursor, int n, int E, int nb) {
    __shared__ int s[256];
    int t = threadIdx.x;
    int v = (t < nb) ? bsum[t] : 0;
    s[t] = v; __syncthreads();
    for (int off = 1; off < 256; off <<= 1) {
        int x = (t >= off) ? s[t - off] : 0;
        __syncthreads();
        s[t] += x;
        __syncthreads();
    }
    // s is now INCLUSIVE scan; exclusive offset for this block:
    int excl = s[blockIdx.x] - bsum[blockIdx.x];
    int i = blockIdx.x * 256 + t;
    if (i < n) {
        int val = offs[i] + excl;
        offs[i] = val;
        cursor[i] = val;
    }
    if (i == 0) offs[n] = E;
}

__global__ void k_scatter(const int* __restrict__ ei, const int* __restrict__ flag,
                          int* __restrict__ cursor,
                          int* __restrict__ perm, int* __restrict__ srcs,
                          int* __restrict__ dsts, int E, int n) {
    int e = blockIdx.x * blockDim.x + threadIdx.x;
    if (e < E) {
        int sv, dv;
        if (flag[0]) {
            sv = ei[2 * (size_t)e];
            dv = ei[2 * ((size_t)E + e)];
        } else {
            sv = ei[e];
            dv = ei[(size_t)E + e];
        }
        sv = clampi(sv, 0, n - 1);
        dv = clampi(dv, 0, n - 1);
        int p = clampi(atomicAdd(&cursor[dv], 1), 0, E - 1);
        perm[p] = e;
        srcs[p] = sv;
        dsts[p] = dv;
    }
}

#define HSTR 136

// ---------------- merged encoders: node_enc (+root0) | edge_enc ----------------
__global__ __launch_bounds__(512) void k_enc(
    const float* __restrict__ x, const u16* __restrict__ nWs, const float* __restrict__ nbias,
    const u16* __restrict__ Wrs0,
    float* __restrict__ h, u16* __restrict__ hn, int n,
    const float* __restrict__ ea, const int* __restrict__ perm,
    const float* __restrict__ eW, const float* __restrict__ ebias,
    u16* __restrict__ e_s, int E, int RB) {
    __shared__ __align__(16) short sA[8 * 16 * HSTR];   // 34.8 KB (edge path uses 4 KB)
    int t = threadIdx.x;
    if ((int)blockIdx.x < RB) {
        // ---- node encoder + root0 ----
        int w = t >> 6, l = t & 63, q = l >> 4, ml = l & 15;
        int wbase = blockIdx.x * 128 + w * 16;
        int rin = wbase + ml;
        int rr = (rin < n) ? rin : 0;
        const float* xr = x + (size_t)rr * 128;
        short8 a[4];
#pragma unroll
        for (int kt = 0; kt < 4; kt++) {
            float4 f0 = *((const float4*)(xr + kt * 32 + q * 8));
            float4 f1 = *((const float4*)(xr + kt * 32 + q * 8 + 4));
            a[kt][0] = (short)f2bf(f0.x); a[kt][1] = (short)f2bf(f0.y);
            a[kt][2] = (short)f2bf(f0.z); a[kt][3] = (short)f2bf(f0.w);
            a[kt][4] = (short)f2bf(f1.x); a[kt][5] = (short)f2bf(f1.y);
            a[kt][6] = (short)f2bf(f1.z); a[kt][7] = (short)f2bf(f1.w);
        }
        float bc[4];
#pragma unroll
        for (int nt = 0; nt < 4; nt++) bc[nt] = nbias[nt * 16 + ml];
        floatx4 acc[4];
#pragma unroll
        for (int nt = 0; nt < 4; nt++) acc[nt] = floatx4{0.f, 0.f, 0.f, 0.f};
#pragma unroll
        for (int kt = 0; kt < 4; kt++) {
#pragma unroll
            for (int nt = 0; nt < 4; nt++) {
                short8 bf = *((const short8*)(nWs + (size_t)((kt * 4 + q) * 64 + nt * 16 + ml) * 8));
                acc[nt] = __builtin_amdgcn_mfma_f32_16x16x32_bf16(a[kt], bf, acc[nt], 0, 0, 0);
            }
        }
        short* arena = sA + w * 16 * HSTR;
#pragma unroll
        for (int nt = 0; nt < 4; nt++) {
#pragma unroll
            for (int r2 = 0; r2 < 4; r2++) {
                int pos = wbase + q * 4 + r2;
                float v = acc[nt][r2] + bc[nt];
                u16 bv = f2bf(v);
                arena[(q * 4 + r2) * HSTR + nt * 16 + ml] = (short)bv;
                if (pos < n) hn[(size_t)pos * 64 + nt * 16 + ml] = bv;
            }
        }
        short8 ah[2];
#pragma unroll
        for (int kt = 0; kt < 2; kt++)
            ah[kt] = *((const short8*)(arena + ml * HSTR + kt * 32 + q * 8));
        floatx4 acc2[4];
#pragma unroll
        for (int nt = 0; nt < 4; nt++) acc2[nt] = floatx4{0.f, 0.f, 0.f, 0.f};
#pragma unroll
        for (int kt = 0; kt < 2; kt++) {
#pragma unroll
            for (int nt = 0; nt < 4; nt++) {
                short8 bf = *((const short8*)(Wrs0 + (size_t)((kt * 4 + q) * 64 + nt * 16 + ml) * 8));
                acc2[nt] = __builtin_amdgcn_mfma_f32_16x16x32_bf16(ah[kt], bf, acc2[nt], 0, 0, 0);
            }
        }
#pragma unroll
        for (int nt = 0; nt < 4; nt++) {
#pragma unroll
            for (int r2 = 0; r2 < 4; r2++) {
                int pos = wbase + q * 4 + r2;
                if (pos < n) h[(size_t)pos * 64 + nt * 16 + ml] = acc2[nt][r2];
            }
        }
    } else {
        // ---- edge encoder (512 threads) ----
        float4* sW4 = (float4*)sA;   // W[16][64] as float4 [k][c/4], 4 KB
        if (t < 256) sW4[t] = ((const float4*)eW)[t];
        __syncthreads();
        int gid = (blockIdx.x - RB) * 512 + t;
        int eidx = gid >> 2, qq = gid & 3;
        if (eidx >= E) return;
        int e = perm[eidx];
        const float4* row4 = (const float4*)(ea + (size_t)e * 16);
        float4 r4[4];
        r4[0] = row4[0]; r4[1] = row4[1]; r4[2] = row4[2]; r4[3] = row4[3];
        const float* row = (const float*)r4;
        float4 acc[4];
#pragma unroll
        for (int j = 0; j < 4; j++) acc[j] = ((const float4*)ebias)[qq * 4 + j];
#pragma unroll
        for (int k = 0; k < 16; k++) {
            float rv = row[k];
#pragma unroll
            for (int j = 0; j < 4; j++) {
                float4 wv = sW4[k * 16 + qq * 4 + j];
                acc[j].x += rv * wv.x; acc[j].y += rv * wv.y;
                acc[j].z += rv * wv.z; acc[j].w += rv * wv.w;
            }
        }
        u32 pk[8];
#pragma unroll
        for (int j = 0; j < 4; j++) {
            pk[2 * j]     = (u32)f2bf(acc[j].x) | ((u32)f2bf(acc[j].y) << 16);
            pk[2 * j + 1] = (u32)f2bf(acc[j].z) | ((u32)f2bf(acc[j].w) << 16);
        }
        uint4* outp = (uint4*)(e_s + (size_t)eidx * 64 + qq * 16);
        outp[0] = make_uint4(pk[0], pk[1], pk[2], pk[3]);
        outp[1] = make_uint4(pk[4], pk[5], pk[6], pk[7]);
    }
}

// ---------------- edge MLP (MFMA, LDS weights, async-DMA staging, fused root) ----------------
#define TILE 256
__global__ __launch_bounds__(512, 4) void k_mlp(
    const u16* __restrict__ hn, const u16* __restrict__ e_s,
    const u16* __restrict__ e_s2,
    const int* __restrict__ dsts, const int* __restrict__ srcs,
    const u16* __restrict__ W1s, const float* __restrict__ b1,
    const u16* __restrict__ W2s, const float* __restrict__ b2,
    const float* __restrict__ elng, const float* __restrict__ elnb,
    int ln_edge, u16* __restrict__ m_out, int E,
    const u16* __restrict__ Wrs, float* __restrict__ h, int do_root, int nn) {
    __shared__ __align__(16) short sW2L[8192];      // 16 KB: W2 frags, then root arena
    __shared__ __align__(16) short sShared[24576];  // 48 KB: W1 frags, then per-wave arenas

    int t = threadIdx.x;
    int w = t >> 6, l = t & 63, q = l >> 4, ml = l & 15;
    int base = blockIdx.x * TILE + w * 32;
    int pos0 = base + ml;
    int pos1 = base + 16 + ml;
    bool act0 = pos0 < E, act1 = pos1 < E;
    int pp0 = act0 ? pos0 : 0, pp1 = act1 ? pos1 : 0;
    int dn0 = act0 ? dsts[pos0] : 0;
    int sn0 = act0 ? srcs[pos0] : 0;
    int dn1 = act1 ? dsts[pos1] : 0;
    int sn1 = act1 ? srcs[pos1] : 0;

    // Stage weights global -> LDS via async DMA (issued first; drains at barrier).
    {
#pragma unroll
        for (int j = 0; j < 6; j++)
            g2lds16((const char*)W1s + (size_t)(t + j * 512) * 16,
                    (char*)sShared + (size_t)(t + j * 512) * 16);
#pragma unroll
        for (int j = 0; j < 2; j++)
            g2lds16((const char*)W2s + (size_t)(t + j * 512) * 16,
                    (char*)sW2L + (size_t)(t + j * 512) * 16);
    }

    // Per-edge gathers for both tiles (overlap the DMA latency).
    short8 a0[6], a1[6];
    a0[0] = *(const short8*)(hn + (size_t)dn0 * 64 + q * 8);
    a0[1] = *(const short8*)(hn + (size_t)dn0 * 64 + 32 + q * 8);
    a0[2] = *(const short8*)(hn + (size_t)sn0 * 64 + q * 8);
    a0[3] = *(const short8*)(hn + (size_t)sn0 * 64 + 32 + q * 8);
    a1[0] = *(const short8*)(hn + (size_t)dn1 * 64 + q * 8);
    a1[1] = *(const short8*)(hn + (size_t)dn1 * 64 + 32 + q * 8);
    a1[2] = *(const short8*)(hn + (size_t)sn1 * 64 + q * 8);
    a1[3] = *(const short8*)(hn + (size_t)sn1 * 64 + 32 + q * 8);
    short8 e00 = *(const short8*)(e_s + (size_t)pp0 * 64 + q * 8);
    short8 e01 = *(const short8*)(e_s + (size_t)pp0 * 64 + 32 + q * 8);
    short8 e10 = *(const short8*)(e_s + (size_t)pp1 * 64 + q * 8);
    short8 e11 = *(const short8*)(e_s + (size_t)pp1 * 64 + 32 + q * 8);
    short8 f00, f01, f10, f11;
    bool has2 = (e_s2 != nullptr);
    if (has2) {
        f00 = *(const short8*)(e_s2 + (size_t)pp0 * 64 + q * 8);
        f01 = *(const short8*)(e_s2 + (size_t)pp0 * 64 + 32 + q * 8);
        f10 = *(const short8*)(e_s2 + (size_t)pp1 * 64 + q * 8);
        f11 = *(const short8*)(e_s2 + (size_t)pp1 * 64 + 32 + q * 8);
    }

    if (ln_edge) {
        {   // tile0 edge LN (with optional fused residual add, f32)
            float ev[16];
            float sm = 0.f, sq = 0.f;
#pragma unroll
            for (int i = 0; i < 8; i++) {
                float f0 = bf2f((u16)e00[i]);
                float f1 = bf2f((u16)e01[i]);
                if (has2) { f0 += bf2f((u16)f00[i]); f1 += bf2f((u16)f01[i]); }
                ev[i] = f0; ev[8 + i] = f1;
                sm += f0 + f1; sq += f0 * f0 + f1 * f1;
            }
            sm += __shfl_xor(sm, 16); sm += __shfl_xor(sm, 32);
            sq += __shfl_xor(sq, 16); sq += __shfl_xor(sq, 32);
            float mu = sm * (1.f / 64.f);
            float var = sq * (1.f / 64.f) - mu * mu;
            float inv = rsqrtf(fmaxf(var, 0.f) + LN_EPS);
#pragma unroll
            for (int i = 0; i < 8; i++) {
                int c0 = q * 8 + i, c1 = 32 + q * 8 + i;
                a0[4][i] = (short)f2bf((ev[i] - mu) * inv * elng[c0] + elnb[c0]);
                a0[5][i] = (short)f2bf((ev[8 + i] - mu) * inv * elng[c1] + elnb[c1]);
            }
        }
        {   // tile1 edge LN
            float ev[16];
            float sm = 0.f, sq = 0.f;
#pragma unroll
            for (int i = 0; i < 8; i++) {
                float f0 = bf2f((u16)e10[i]);
                float f1 = bf2f((u16)e11[i]);
                if (has2) { f0 += bf2f((u16)f10[i]); f1 += bf2f((u16)f11[i]); }
                ev[i] = f0; ev[8 + i] = f1;
                sm += f0 + f1; sq += f0 * f0 + f1 * f1;
            }
            sm += __shfl_xor(sm, 16); sm += __shfl_xor(sm, 32);
            sq += __shfl_xor(sq, 16); sq += __shfl_xor(sq, 32);
            float mu = sm * (1.f / 64.f);
            float var = sq * (1.f / 64.f) - mu * mu;
            float inv = rsqrtf(fmaxf(var, 0.f) + LN_EPS);
#pragma unroll
            for (int i = 0; i < 8; i++) {
                int c0 = q * 8 + i, c1 = 32 + q * 8 + i;
                a1[4][i] = (short)f2bf((ev[i] - mu) * inv * elng[c0] + elnb[c0]);
                a1[5][i] = (short)f2bf((ev[8 + i] - mu) * inv * elng[c1] + elnb[c1]);
            }
        }
    } else {
        a0[4] = e00; a0[5] = e01;
        a1[4] = e10; a1[5] = e11;
    }

    __syncthreads();   // weights staged (DMA drained by barrier's vmcnt(0))

    floatx4 acc0[8], acc1[8];
#pragma unroll
    for (int nt = 0; nt < 8; nt++) {
        acc0[nt] = floatx4{0.f, 0.f, 0.f, 0.f};
        acc1[nt] = floatx4{0.f, 0.f, 0.f, 0.f};
    }
#pragma unroll
    for (int kt = 0; kt < 6; kt++) {
#pragma unroll
        for (int nt = 0; nt < 8; nt++) {
            short8 bf = *((const short8*)(sShared + ((kt * 4 + q) * 128 + nt * 16 + ml) * 8));
            acc0[nt] = __builtin_amdgcn_mfma_f32_16x16x32_bf16(a0[kt], bf, acc0[nt], 0, 0, 0);
            acc1[nt] = __builtin_amdgcn_mfma_f32_16x16x32_bf16(a1[kt], bf, acc1[nt], 0, 0, 0);
        }
    }

    __syncthreads();   // all waves done reading W1 frags; arenas may overlay

    // Bias loads deferred here to keep W1-loop live set under the VGPR cap.
    float b1c[8], b2c[4];
#pragma unroll
    for (int nt = 0; nt < 8; nt++) b1c[nt] = b1[nt * 16 + ml];
#pragma unroll
    for (int nt = 0; nt < 4; nt++) b2c[nt] = b2[nt * 16 + ml];

    short* arena = sShared + w * 16 * HSTR;

    // tile0 W1-out -> arena -> A-frags
#pragma unroll
    for (int nt = 0; nt < 8; nt++) {
#pragma unroll
        for (int r2 = 0; r2 < 4; r2++) {
            float v = fmaxf(acc0[nt][r2] + b1c[nt], 0.f);
            ((u16*)arena)[(q * 4 + r2) * HSTR + nt * 16 + ml] = f2bf(v);
        }
    }
    short8 ah0[4];
#pragma unroll
    for (int kt = 0; kt < 4; kt++)
        ah0[kt] = *((const short8*)(arena + ml * HSTR + kt * 32 + q * 8));

    // tile1 W1-out -> arena -> A-frags (same region; within-wave ordering via lgkmcnt)
#pragma unroll
    for (int nt = 0; nt < 8; nt++) {
#pragma unroll
        for (int r2 = 0; r2 < 4; r2++) {
            float v = fmaxf(acc1[nt][r2] + b1c[nt], 0.f);
            ((u16*)arena)[(q * 4 + r2) * HSTR + nt * 16 + ml] = f2bf(v);
        }
    }
    short8 ah1[4];
#pragma unroll
    for (int kt = 0; kt < 4; kt++)
        ah1[kt] = *((const short8*)(arena + ml * HSTR + kt * 32 + q * 8));

    // Shared W2 loop: one B-frag read feeds both tiles. (Last reader of sW2L.)
    floatx4 c20[4], c21[4];
#pragma unroll
    for (int nt = 0; nt < 4; nt++) {
        c20[nt] = floatx4{0.f, 0.f, 0.f, 0.f};
        c21[nt] = floatx4{0.f, 0.f, 0.f, 0.f};
    }
#pragma unroll
    for (int kt = 0; kt < 4; kt++) {
#pragma unroll
        for (int nt = 0; nt < 4; nt++) {
            short8 bf = *((const short8*)(sW2L + ((kt * 4 + q) * 64 + nt * 16 + ml) * 8));
            c20[nt] = __builtin_amdgcn_mfma_f32_16x16x32_bf16(ah0[kt], bf, c20[nt], 0, 0, 0);
            c21[nt] = __builtin_amdgcn_mfma_f32_16x16x32_bf16(ah1[kt], bf, c21[nt], 0, 0, 0);
        }
    }

    // tile0 output
#pragma unroll
    for (int nt = 0; nt < 4; nt++) {
#pragma unroll
        for (int r2 = 0; r2 < 4; r2++) {
            ((u16*)arena)[(q * 4 + r2) * HSTR + nt * 16 + ml] = f2bf(c20[nt][r2] + b2c[nt]);
        }
    }
    {
        short8 m0 = *((const short8*)(arena + ml * HSTR + q * 16));
        short8 m1 = *((const short8*)(arena + ml * HSTR + q * 16 + 8));
        if (act0) {
            *((short8*)(m_out + (size_t)pos0 * 64 + q * 16)) = m0;
            *((short8*)(m_out + (size_t)pos0 * 64 + q * 16 + 8)) = m1;
        }
    }
    // tile1 output
#pragma unroll
    for (int nt = 0; nt < 4; nt++) {
#pragma unroll
        for (int r2 = 0; r2 < 4; r2++) {
            ((u16*)arena)[(q * 4 + r2) * HSTR + nt * 16 + ml] = f2bf(c21[nt][r2] + b2c[nt]);
        }
    }
    {
        short8 m0 = *((const short8*)(arena + ml * HSTR + q * 16));
        short8 m1 = *((const short8*)(arena + ml * HSTR + q * 16 + 8));
        if (act1) {
            *((short8*)(m_out + (size_t)pos1 * 64 + q * 16)) = m0;
            *((short8*)(m_out + (size_t)pos1 * 64 + q * 16 + 8)) = m1;
        }
    }

    // ---- fused root (layers 1/2): h += hn @ Wr, exact k_root body ----
    if (do_root && blockIdx.x < ((nn + 127) >> 7)) {
        __syncthreads();   // all waves done reading sW2L
        int nbase = blockIdx.x * 128;
        {
            int r = t >> 2, s = t & 3;
            int pos = nbase + r;
            int g2 = r >> 4, mm = r & 15;
            short* grp = sW2L + g2 * 1024;
            bool ract = pos < nn;
            uint4 z4 = make_uint4(0, 0, 0, 0);
            const uint4* pd = (const uint4*)(hn + (size_t)(ract ? pos : 0) * 64);
            uint4 d0 = ract ? pd[2 * s] : z4;
            uint4 d1 = ract ? pd[2 * s + 1] : z4;
            int ch = (s >> 1) * 4 + (s & 1) * 2;
            *((uint4*)(grp + ch * 128 + mm * 8)) = d0;
            *((uint4*)(grp + (ch + 1) * 128 + mm * 8)) = d1;
        }
        __syncthreads();
        short* rA = sW2L + w * 1024;
        floatx4 racc[4];
#pragma unroll
        for (int nt = 0; nt < 4; nt++) racc[nt] = floatx4{0.f, 0.f, 0.f, 0.f};
#pragma unroll
        for (int kt = 0; kt < 2; kt++) {
            short8 aa = *((const short8*)(rA + (kt * 4 + q) * 128 + ml * 8));
#pragma unroll
            for (int nt = 0; nt < 4; nt++) {
                short8 bf = *((const short8*)(Wrs + (size_t)((kt * 4 + q) * 64 + nt * 16 + ml) * 8));
                racc[nt] = __builtin_amdgcn_mfma_f32_16x16x32_bf16(aa, bf, racc[nt], 0, 0, 0);
            }
        }
#pragma unroll
        for (int nt = 0; nt < 4; nt++) {
#pragma unroll
            for (int r2 = 0; r2 < 4; r2++) {
                int pos = nbase + w * 16 + q * 4 + r2;
                if (pos < nn) {
                    size_t idx = (size_t)pos * 64 + nt * 16 + ml;
                    h[idx] += racc[nt][r2];
                }
            }
        }
    }
}

// ---------------- aggregation (chunked softmax, 2-node interleave) + fused LN ----------------
// R14: each wave processes TWO nodes; both nodes' chunk loads are issued
// back-to-back BEFORE either compute (unconditional, clamped-safe addresses),
// doubling memory-level parallelism against the serial online-merge chain.
// Per-node math (chunk order, merge order) is bit-identical to R13.
__global__ __launch_bounds__(256) void k_agg2(
    const u16* __restrict__ m_s, float* __restrict__ h,
    const int* __restrict__ offs, const float* __restrict__ tptr, int tidx,
    const float* __restrict__ g, const float* __restrict__ b,
    u16* __restrict__ hn_out, float* __restrict__ f32_out,
    int write_h, int n, int E) {
    int t = threadIdx.x, wid = t >> 6, lane = t & 63;
    float tv = tptr[tidx];
    float gc = g[lane], bc = b[lane];
    for (int nd = blockIdx.x * 8 + wid * 2; nd < n; nd += gridDim.x * 8) {
        int ndB = nd + 1;
        bool hasB = ndB < n;
        int pA0 = clampi(offs[nd], 0, E);
        int pA1 = clampi(offs[nd + 1], pA0, E);
        int pB0 = hasB ? clampi(offs[ndB], 0, E) : 0;
        int pB1 = hasB ? clampi(offs[ndB + 1], pB0, E) : 0;
        float hvA = h[(size_t)nd * 64 + lane];
        float hvB = hasB ? h[(size_t)ndB * 64 + lane] : 0.f;
        int dA = pA1 - pA0, dB = pB1 - pB0;
        int dmax = (dA > dB) ? dA : dB;
        float MA = -1e30f, DA = 0.f, SA = 0.f;
        float MB = -1e30f, DB = 0.f, SB = 0.f;
        for (int p = 0; p < dmax; p += 8) {
            bool doA = p < dA, doB = p < dB;
            float mvA[8], mvB[8];
            // issue ALL 16 loads first (safe clamped addresses; rows contiguous per node)
#pragma unroll
            for (int j = 0; j < 8; j++) {
                int r = p + j;
                int ia = doA ? (pA0 + (r < dA ? r : dA - 1)) : 0;
                mvA[j] = bf2f(m_s[(size_t)ia * 64 + lane]);
            }
#pragma unroll
            for (int j = 0; j < 8; j++) {
                int r = p + j;
                int ib = doB ? (pB0 + (r < dB ? r : dB - 1)) : 0;
                mvB[j] = bf2f(m_s[(size_t)ib * 64 + lane]);
            }
            if (doA) {
                int cnt = dA - p;
                float lg[8];
#pragma unroll
                for (int j = 0; j < 8; j++) lg[j] = (j < cnt) ? mvA[j] * tv : -1e30f;
                float Mc = fmaxf(fmaxf(fmaxf(lg[0], lg[1]), fmaxf(lg[2], lg[3])),
                                 fmaxf(fmaxf(lg[4], lg[5]), fmaxf(lg[6], lg[7])));
                float e0 = __expf(lg[0] - Mc), e1 = __expf(lg[1] - Mc);
                float e2 = __expf(lg[2] - Mc), e3 = __expf(lg[3] - Mc);
                float e4 = __expf(lg[4] - Mc), e5 = __expf(lg[5] - Mc);
                float e6 = __expf(lg[6] - Mc), e7 = __expf(lg[7] - Mc);
                float Dc = ((e0 + e1) + (e2 + e3)) + ((e4 + e5) + (e6 + e7));
                float Sc = ((mvA[0] * e0 + mvA[1] * e1) + (mvA[2] * e2 + mvA[3] * e3)) +
                           ((mvA[4] * e4 + mvA[5] * e5) + (mvA[6] * e6 + mvA[7] * e7));
                float Mn = fmaxf(MA, Mc);
                float xa = __expf(MA - Mn), xb = __expf(Mc - Mn);
                DA = DA * xa + Dc * xb;
                SA = SA * xa + Sc * xb;
                MA = Mn;
            }
            if (doB) {
                int cnt = dB - p;
                float lg[8];
#pragma unroll
                for (int j = 0; j < 8; j++) lg[j] = (j < cnt) ? mvB[j] * tv : -1e30f;
                float Mc = fmaxf(fmaxf(fmaxf(lg[0], lg[1]), fmaxf(lg[2], lg[3])),
                                 fmaxf(fmaxf(lg[4], lg[5]), fmaxf(lg[6], lg[7])));
                float e0 = __expf(lg[0] - Mc), e1 = __expf(lg[1] - Mc);
                float e2 = __expf(lg[2] - Mc), e3 = __expf(lg[3] - Mc);
                float e4 = __expf(lg[4] - Mc), e5 = __expf(lg[5] - Mc);
                float e6 = __expf(lg[6] - Mc), e7 = __expf(lg[7] - Mc);
                float Dc = ((e0 + e1) + (e2 + e3)) + ((e4 + e5) + (e6 + e7));
                float Sc = ((mvB[0] * e0 + mvB[1] * e1) + (mvB[2] * e2 + mvB[3] * e3)) +
                           ((mvB[4] * e4 + mvB[5] * e5) + (mvB[6] * e6 + mvB[7] * e7));
                float Mn = fmaxf(MB, Mc);
                float xa = __expf(MB - Mn), xb = __expf(Mc - Mn);
                DB = DB * xa + Dc * xb;
                SB = SB * xa + Sc * xb;
                MB = Mn;
            }
        }
        // finalize node A: residual add + LN + relu
        if (dA > 0) hvA += SA / DA;
        if (write_h) h[(size_t)nd * 64 + lane] = hvA;
        {
            float s = hvA;
#pragma unroll
            for (int o = 32; o > 0; o >>= 1) s += __shfl_xor(s, o);
            float mu = s * (1.f / 64.f);
            float d = hvA - mu;
            float s2 = d * d;
#pragma unroll
            for (int o = 32; o > 0; o >>= 1) s2 += __shfl_xor(s2, o);
            float inv = rsqrtf(s2 * (1.f / 64.f) + LN_EPS);
            float r = fmaxf(d * inv * gc + bc, 0.f);
            if (hn_out) hn_out[(size_t)nd * 64 + lane] = f2bf(r);
            else        f32_out[(size_t)nd * 64 + lane] = r;
        }
        // finalize node B
        if (hasB) {
            if (dB > 0) hvB += SB / DB;
            if (write_h) h[(size_t)ndB * 64 + lane] = hvB;
            float s = hvB;
#pragma unroll
            for (int o = 32; o > 0; o >>= 1) s += __shfl_xor(s, o);
            float mu = s * (1.f / 64.f);
            float d = hvB - mu;
            float s2 = d * d;
#pragma unroll
            for (int o = 32; o > 0; o >>= 1) s2 += __shfl_xor(s2, o);
            float inv = rsqrtf(s2 * (1.f / 64.f) + LN_EPS);
            float r = fmaxf(d * inv * gc + bc, 0.f);
            if (hn_out) hn_out[(size_t)ndB * 64 + lane] = f2bf(r);
            else        f32_out[(size_t)ndB * 64 + lane] = r;
        }
    }
}

// ---------------- launcher ----------------
extern "C" void kernel_launch(void* const* d_in, const int* in_sizes, int n_in,
                              void* d_out, int out_size, void* d_ws, size_t ws_size,
                              hipStream_t stream) {
    float* outp = (float*)d_out;
    int FB = (out_size + 255) / 256;

    if (n_in != 17) {
        k_fill<<<FB, 256, 0, stream>>>(outp, out_size, 3.0f);
        return;
    }

    const float* x    = (const float*)d_in[0];
    const int*   ei   = (const int*)d_in[1];
    const float* ea   = (const float*)d_in[2];
    const float* nW   = (const float*)d_in[3];
    const float* nb   = (const float*)d_in[4];
    const float* eW   = (const float*)d_in[5];
    const float* eb   = (const float*)d_in[6];
    const float* cW1  = (const float*)d_in[7];
    const float* cb1  = (const float*)d_in[8];
    const float* cW2  = (const float*)d_in[9];
    const float* cb2  = (const float*)d_in[10];
    const float* cWr  = (const float*)d_in[11];
    const float* ct   = (const float*)d_in[12];
    const float* lng  = (const float*)d_in[13];
    const float* lnb  = (const float*)d_in[14];
    const float* elng = (const float*)d_in[15];
    const float* elnb = (const float*)d_in[16];

    const int n = in_sizes[0] / 128;   // 50000
    const int E = in_sizes[2] / 16;    // 500000

    char* ws = (char*)d_ws;
    size_t o = 0;
    auto alloc = [&](size_t bytes) -> void* {
        void* p = ws + o;
        o += (bytes + 255) & ~(size_t)255;
        return p;
    };
    int*   flag   = (int*)alloc(256);
    int*   deg    = (int*)alloc((size_t)n * 4);
    int*   offs   = (int*)alloc((size_t)(n + 1) * 4);
    int*   cursor = (int*)alloc((size_t)n * 4);
    int*   bsum   = (int*)alloc(256 * 4);
    int*   perm   = (int*)alloc((size_t)E * 4);
    int*   srcs   = (int*)alloc((size_t)E * 4);
    int*   dsts   = (int*)alloc((size_t)E * 4);
    float* h      = (float*)alloc((size_t)n * 64 * 4);
    u16*   hn     = (u16*)alloc((size_t)n * 64 * 2);
    u16*   bufA   = (u16*)alloc((size_t)E * 64 * 2);
    u16*   bufB   = (u16*)alloc((size_t)E * 64 * 2);
    u16*   W1s    = (u16*)alloc((size_t)3 * 24576 * 2);
    u16*   W2s    = (u16*)alloc((size_t)3 * 8192 * 2);
    u16*   Wrs    = (u16*)alloc((size_t)3 * 4096 * 2);
    u16*   nWs    = (u16*)alloc((size_t)8192 * 2);

    if (o > ws_size) {
        k_fill<<<FB, 256, 0, stream>>>(outp, out_size, 2.0f);
        return;
    }

    int SB = (n + 255) / 256;
    int PB = (3 * 24576 + 255) / 256;   // 288 >= SB for n=50000
    if (SB > PB) PB = SB;
    k_pre0<<<PB, 256, 0, stream>>>(ei, E, flag, deg, n,
                                   cW1, cW2, cWr, nW, W1s, W2s, Wrs, nWs);
    k_hist<<<(E + 255) / 256, 256, 0, stream>>>(ei, flag, deg, E, n);
    k_scan1<<<SB, 256, 0, stream>>>(deg, offs, bsum, n);
    k_scan23<<<SB, 256, 0, stream>>>(offs, bsum, cursor, n, E, SB);
    k_scatter<<<(E + 255) / 256, 256, 0, stream>>>(ei, flag, cursor, perm, srcs, dsts, E, n);

    int RB = (n + 127) / 128;
    int EB2 = (E * 4 + 511) / 512;
    k_enc<<<RB + EB2, 512, 0, stream>>>(x, nWs, nb, Wrs, h, hn, n,
                                        ea, perm, eW, eb, bufA, E, RB);

    // Buffer schedule (ping-pong, no copies):
    //  L0: mlp(in=bufA)            -> bufB(m1); agg: LN->hn(lng[1])  [root0 in k_enc]
    //  L1: mlp(in=bufB, root Wr1)  -> bufA(m2); agg: LN->hn(lng[2])
    //  L2: mlp(in=bufB,in2=bufA, root Wr2) -> bufA(m3); agg: LN->out(lng[0])
    int MB = (E + TILE - 1) / TILE;
    int AB = (n + 7) / 8;

    const u16* mlp_in[3]  = { bufA, bufB, bufB };
    const u16* mlp_in2[3] = { nullptr, nullptr, bufA };
    u16*       mlp_out[3] = { bufB, bufA, bufA };

    for (int i = 0; i < 3; i++) {
        k_mlp<<<MB, 512, 0, stream>>>(
            hn, mlp_in[i], mlp_in2[i], dsts, srcs,
            W1s + (size_t)i * 24576, cb1 + (size_t)i * 128,
            W2s + (size_t)i * 8192, cb2 + (size_t)i * 64,
            elng + (size_t)((i > 0) ? (i - 1) : 0) * 64,
            elnb + (size_t)((i > 0) ? (i - 1) : 0) * 64,
            (i > 0) ? 1 : 0, mlp_out[i], E,
            Wrs + (size_t)i * 4096, h, (i > 0) ? 1 : 0, n);
        if (i < 2) {
            k_agg2<<<AB, 256, 0, stream>>>(mlp_out[i], h, offs, ct, i,
                                           lng + (size_t)(i + 1) * 64, lnb + (size_t)(i + 1) * 64,
                                           hn, nullptr, 1, n, E);
        } else {
            k_agg2<<<AB, 256, 0, stream>>>(mlp_out[i], h, offs, ct, i,
                                           lng, lnb,
                                           nullptr, outp, 0, n, E);
        }
    }
}

// Round 15
// 483.334 us; speedup vs baseline: 1.0416x; 1.0416x over previous
//
#include <hip/hip_runtime.h>

typedef unsigned short u16;
typedef unsigned int u32;
typedef __attribute__((ext_vector_type(8))) short short8;
typedef __attribute__((ext_vector_type(4))) float floatx4;

#define LN_EPS 1e-5f

__device__ __forceinline__ float bf2f(u16 u) {
    union { u32 i; float f; } v; v.i = ((u32)u) << 16; return v.f;
}
__device__ __forceinline__ u16 f2bf(float f) {
    union { u32 i; float f; } v; v.f = f;
    u32 x = v.i;
    return (u16)((x + 0x7fffu + ((x >> 16) & 1u)) >> 16);
}
__device__ __forceinline__ int clampi(int v, int lo, int hi) {
    return v < lo ? lo : (v > hi ? hi : v);
}

// Async 16B global->LDS DMA (no VGPR round-trip). LDS dest must be
// wave-uniform base + lane*16 — our staging pattern satisfies this.
__device__ __forceinline__ void g2lds16(const void* g, void* l) {
    __builtin_amdgcn_global_load_lds(
        (__attribute__((address_space(1))) const u32*)g,
        (__attribute__((address_space(3))) u32*)l, 16, 0, 0);
}

// Diagnostic fill (f32) — error paths only.
__global__ void k_fill(float* __restrict__ out, int nel, float val) {
    int i = blockIdx.x * blockDim.x + threadIdx.x;
    if (i < nel) out[i] = val;
}

// ---------------- preprocessing ----------------
// pre0 = detect + deg-zero + weight swizzle (all disjoint work, union grid).
// NOTE (R12 lesson): cooperative grid.sync costs ~70 µs/sync on MI355X
// (cross-XCD L2 flush); stream-ordered separate kernels are 15x cheaper.
__global__ void k_pre0(const int* __restrict__ ei, int E, int* __restrict__ flag,
                       int* __restrict__ deg, int n,
                       const float* __restrict__ W1, const float* __restrict__ W2,
                       const float* __restrict__ Wr, const float* __restrict__ nW,
                       u16* __restrict__ W1s, u16* __restrict__ W2s,
                       u16* __restrict__ Wrs, u16* __restrict__ nWs) {
    int t = threadIdx.x;
    if (blockIdx.x == 0) {
        __shared__ int any;
        if (t == 0) any = 0;
        __syncthreads();
        int lim = (E < 4096) ? E : 4096;
        int v = 0;
        for (int i = t; i < lim; i += 256) v |= ei[2 * i + 1];
        if (v) atomicOr(&any, 1);
        __syncthreads();
        if (t == 0) flag[0] = (any == 0) ? 1 : 0;
    }
    int i = blockIdx.x * 256 + t;
    if (i < n) deg[i] = 0;
    // weight swizzle into MFMA B-frag order: k = kt*32+q*8+j -> ((kt*4+q)*N+n)*8+j
    if (i < 3 * 24576) {
        int l = i / 24576, rem = i % 24576;
        int k = rem / 128, c = rem % 128;
        int kt = k >> 5, q = (k >> 3) & 3, j = k & 7;
        W1s[l * 24576 + ((kt * 4 + q) * 128 + c) * 8 + j] = f2bf(W1[i]);
    }
    if (i < 3 * 8192) {
        int l = i / 8192, rem = i % 8192;
        int k = rem / 64, c = rem % 64;
        int kt = k >> 5, q = (k >> 3) & 3, j = k & 7;
        W2s[l * 8192 + ((kt * 4 + q) * 64 + c) * 8 + j] = f2bf(W2[i]);
    }
    if (i < 3 * 4096) {
        int l = i / 4096, rem = i % 4096;
        int k = rem / 64, c = rem % 64;
        int kt = k >> 5, q = (k >> 3) & 3, j = k & 7;
        Wrs[l * 4096 + ((kt * 4 + q) * 64 + c) * 8 + j] = f2bf(Wr[i]);
    }
    if (i < 8192) {
        int k = i / 64, c = i % 64;
        int kt = k >> 5, q = (k >> 3) & 3, j = k & 7;
        nWs[((kt * 4 + q) * 64 + c) * 8 + j] = f2bf(nW[i]);
    }
}

__global__ void k_hist(const int* __restrict__ ei, const int* __restrict__ flag,
                       int* __restrict__ deg, int E, int n) {
    int e = blockIdx.x * blockDim.x + threadIdx.x;
    if (e < E) {
        int d = flag[0] ? ei[2 * ((size_t)E + e)] : ei[(size_t)E + e];
        atomicAdd(&deg[clampi(d, 0, n - 1)], 1);
    }
}

__global__ void k_scan1(const int* __restrict__ deg, int* __restrict__ offs,
                        int* __restrict__ bsum, int n) {
    __shared__ int s[256];
    int t = threadIdx.x;
    int i = blockIdx.x * 256 + t;
    int v = (i < n) ? deg[i] : 0;
    s[t] = v; __syncthreads();
    for (int off = 1; off < 256; off <<= 1) {
        int x = (t >= off) ? s[t - off] : 0;
        __syncthreads();
        s[t] += x;
        __syncthreads();
    }
    if (i < n) offs[i] = s[t] - v;
    if (t == 255) bsum[blockIdx.x] = s[255];
}

// scan2+scan3 merged — every block redundantly scans bsum (nb <= 256) in LDS
// and applies its own exclusive block offset.
__global__ void k_scan23(int* __restrict__ offs, const int* __restrict__ bsum,
                         int* __restrict__ cursor, int n, int E, int nb) {
    __shared__ int s[256];
    int t = threadIdx.x;
    int v = (t < nb) ? bsum[t] : 0;
    s[t] = v; __syncthreads();
    for (int off = 1; off < 256; off <<= 1) {
        int x = (t >= off) ? s[t - off] : 0;
        __syncthreads();
        s[t] += x;
        __syncthreads();
    }
    // s is now INCLUSIVE scan; exclusive offset for this block:
    int excl = s[blockIdx.x] - bsum[blockIdx.x];
    int i = blockIdx.x * 256 + t;
    if (i < n) {
        int val = offs[i] + excl;
        offs[i] = val;
        cursor[i] = val;
    }
    if (i == 0) offs[n] = E;
}

__global__ void k_scatter(const int* __restrict__ ei, const int* __restrict__ flag,
                          int* __restrict__ cursor,
                          int* __restrict__ perm, int* __restrict__ srcs,
                          int* __restrict__ dsts, int E, int n) {
    int e = blockIdx.x * blockDim.x + threadIdx.x;
    if (e < E) {
        int sv, dv;
        if (flag[0]) {
            sv = ei[2 * (size_t)e];
            dv = ei[2 * ((size_t)E + e)];
        } else {
            sv = ei[e];
            dv = ei[(size_t)E + e];
        }
        sv = clampi(sv, 0, n - 1);
        dv = clampi(dv, 0, n - 1);
        int p = clampi(atomicAdd(&cursor[dv], 1), 0, E - 1);
        perm[p] = e;
        srcs[p] = sv;
        dsts[p] = dv;
    }
}

#define HSTR 136

// ---------------- merged encoders: node_enc (+root0) | edge_enc ----------------
__global__ __launch_bounds__(512) void k_enc(
    const float* __restrict__ x, const u16* __restrict__ nWs, const float* __restrict__ nbias,
    const u16* __restrict__ Wrs0,
    float* __restrict__ h, u16* __restrict__ hn, int n,
    const float* __restrict__ ea, const int* __restrict__ perm,
    const float* __restrict__ eW, const float* __restrict__ ebias,
    u16* __restrict__ e_s, int E, int RB) {
    __shared__ __align__(16) short sA[8 * 16 * HSTR];   // 34.8 KB (edge path uses 4 KB)
    int t = threadIdx.x;
    if ((int)blockIdx.x < RB) {
        // ---- node encoder + root0 ----
        int w = t >> 6, l = t & 63, q = l >> 4, ml = l & 15;
        int wbase = blockIdx.x * 128 + w * 16;
        int rin = wbase + ml;
        int rr = (rin < n) ? rin : 0;
        const float* xr = x + (size_t)rr * 128;
        short8 a[4];
#pragma unroll
        for (int kt = 0; kt < 4; kt++) {
            float4 f0 = *((const float4*)(xr + kt * 32 + q * 8));
            float4 f1 = *((const float4*)(xr + kt * 32 + q * 8 + 4));
            a[kt][0] = (short)f2bf(f0.x); a[kt][1] = (short)f2bf(f0.y);
            a[kt][2] = (short)f2bf(f0.z); a[kt][3] = (short)f2bf(f0.w);
            a[kt][4] = (short)f2bf(f1.x); a[kt][5] = (short)f2bf(f1.y);
            a[kt][6] = (short)f2bf(f1.z); a[kt][7] = (short)f2bf(f1.w);
        }
        float bc[4];
#pragma unroll
        for (int nt = 0; nt < 4; nt++) bc[nt] = nbias[nt * 16 + ml];
        floatx4 acc[4];
#pragma unroll
        for (int nt = 0; nt < 4; nt++) acc[nt] = floatx4{0.f, 0.f, 0.f, 0.f};
#pragma unroll
        for (int kt = 0; kt < 4; kt++) {
#pragma unroll
            for (int nt = 0; nt < 4; nt++) {
                short8 bf = *((const short8*)(nWs + (size_t)((kt * 4 + q) * 64 + nt * 16 + ml) * 8));
                acc[nt] = __builtin_amdgcn_mfma_f32_16x16x32_bf16(a[kt], bf, acc[nt], 0, 0, 0);
            }
        }
        short* arena = sA + w * 16 * HSTR;
#pragma unroll
        for (int nt = 0; nt < 4; nt++) {
#pragma unroll
            for (int r2 = 0; r2 < 4; r2++) {
                int pos = wbase + q * 4 + r2;
                float v = acc[nt][r2] + bc[nt];
                u16 bv = f2bf(v);
                arena[(q * 4 + r2) * HSTR + nt * 16 + ml] = (short)bv;
                if (pos < n) hn[(size_t)pos * 64 + nt * 16 + ml] = bv;
            }
        }
        short8 ah[2];
#pragma unroll
        for (int kt = 0; kt < 2; kt++)
            ah[kt] = *((const short8*)(arena + ml * HSTR + kt * 32 + q * 8));
        floatx4 acc2[4];
#pragma unroll
        for (int nt = 0; nt < 4; nt++) acc2[nt] = floatx4{0.f, 0.f, 0.f, 0.f};
#pragma unroll
        for (int kt = 0; kt < 2; kt++) {
#pragma unroll
            for (int nt = 0; nt < 4; nt++) {
                short8 bf = *((const short8*)(Wrs0 + (size_t)((kt * 4 + q) * 64 + nt * 16 + ml) * 8));
                acc2[nt] = __builtin_amdgcn_mfma_f32_16x16x32_bf16(ah[kt], bf, acc2[nt], 0, 0, 0);
            }
        }
#pragma unroll
        for (int nt = 0; nt < 4; nt++) {
#pragma unroll
            for (int r2 = 0; r2 < 4; r2++) {
                int pos = wbase + q * 4 + r2;
                if (pos < n) h[(size_t)pos * 64 + nt * 16 + ml] = acc2[nt][r2];
            }
        }
    } else {
        // ---- edge encoder (512 threads) ----
        float4* sW4 = (float4*)sA;   // W[16][64] as float4 [k][c/4], 4 KB
        if (t < 256) sW4[t] = ((const float4*)eW)[t];
        __syncthreads();
        int gid = (blockIdx.x - RB) * 512 + t;
        int eidx = gid >> 2, qq = gid & 3;
        if (eidx >= E) return;
        int e = perm[eidx];
        const float4* row4 = (const float4*)(ea + (size_t)e * 16);
        float4 r4[4];
        r4[0] = row4[0]; r4[1] = row4[1]; r4[2] = row4[2]; r4[3] = row4[3];
        const float* row = (const float*)r4;
        float4 acc[4];
#pragma unroll
        for (int j = 0; j < 4; j++) acc[j] = ((const float4*)ebias)[qq * 4 + j];
#pragma unroll
        for (int k = 0; k < 16; k++) {
            float rv = row[k];
#pragma unroll
            for (int j = 0; j < 4; j++) {
                float4 wv = sW4[k * 16 + qq * 4 + j];
                acc[j].x += rv * wv.x; acc[j].y += rv * wv.y;
                acc[j].z += rv * wv.z; acc[j].w += rv * wv.w;
            }
        }
        u32 pk[8];
#pragma unroll
        for (int j = 0; j < 4; j++) {
            pk[2 * j]     = (u32)f2bf(acc[j].x) | ((u32)f2bf(acc[j].y) << 16);
            pk[2 * j + 1] = (u32)f2bf(acc[j].z) | ((u32)f2bf(acc[j].w) << 16);
        }
        uint4* outp = (uint4*)(e_s + (size_t)eidx * 64 + qq * 16);
        outp[0] = make_uint4(pk[0], pk[1], pk[2], pk[3]);
        outp[1] = make_uint4(pk[4], pk[5], pk[6], pk[7]);
    }
}

// ---------------- edge MLP (MFMA, LDS weights, async-DMA staging, fused root) ----------------
#define TILE 256
__global__ __launch_bounds__(512, 4) void k_mlp(
    const u16* __restrict__ hn, const u16* __restrict__ e_s,
    const u16* __restrict__ e_s2,
    const int* __restrict__ dsts, const int* __restrict__ srcs,
    const u16* __restrict__ W1s, const float* __restrict__ b1,
    const u16* __restrict__ W2s, const float* __restrict__ b2,
    const float* __restrict__ elng, const float* __restrict__ elnb,
    int ln_edge, u16* __restrict__ m_out, int E,
    const u16* __restrict__ Wrs, float* __restrict__ h, int do_root, int nn) {
    __shared__ __align__(16) short sW2L[8192];      // 16 KB: W2 frags, then root arena
    __shared__ __align__(16) short sShared[24576];  // 48 KB: W1 frags, then per-wave arenas

    int t = threadIdx.x;
    int w = t >> 6, l = t & 63, q = l >> 4, ml = l & 15;
    int base = blockIdx.x * TILE + w * 32;
    int pos0 = base + ml;
    int pos1 = base + 16 + ml;
    bool act0 = pos0 < E, act1 = pos1 < E;
    int pp0 = act0 ? pos0 : 0, pp1 = act1 ? pos1 : 0;
    int dn0 = act0 ? dsts[pos0] : 0;
    int sn0 = act0 ? srcs[pos0] : 0;
    int dn1 = act1 ? dsts[pos1] : 0;
    int sn1 = act1 ? srcs[pos1] : 0;

    // Stage weights global -> LDS via async DMA (issued first; drains at barrier).
    {
#pragma unroll
        for (int j = 0; j < 6; j++)
            g2lds16((const char*)W1s + (size_t)(t + j * 512) * 16,
                    (char*)sShared + (size_t)(t + j * 512) * 16);
#pragma unroll
        for (int j = 0; j < 2; j++)
            g2lds16((const char*)W2s + (size_t)(t + j * 512) * 16,
                    (char*)sW2L + (size_t)(t + j * 512) * 16);
    }

    // Per-edge gathers for both tiles (overlap the DMA latency).
    short8 a0[6], a1[6];
    a0[0] = *(const short8*)(hn + (size_t)dn0 * 64 + q * 8);
    a0[1] = *(const short8*)(hn + (size_t)dn0 * 64 + 32 + q * 8);
    a0[2] = *(const short8*)(hn + (size_t)sn0 * 64 + q * 8);
    a0[3] = *(const short8*)(hn + (size_t)sn0 * 64 + 32 + q * 8);
    a1[0] = *(const short8*)(hn + (size_t)dn1 * 64 + q * 8);
    a1[1] = *(const short8*)(hn + (size_t)dn1 * 64 + 32 + q * 8);
    a1[2] = *(const short8*)(hn + (size_t)sn1 * 64 + q * 8);
    a1[3] = *(const short8*)(hn + (size_t)sn1 * 64 + 32 + q * 8);
    short8 e00 = *(const short8*)(e_s + (size_t)pp0 * 64 + q * 8);
    short8 e01 = *(const short8*)(e_s + (size_t)pp0 * 64 + 32 + q * 8);
    short8 e10 = *(const short8*)(e_s + (size_t)pp1 * 64 + q * 8);
    short8 e11 = *(const short8*)(e_s + (size_t)pp1 * 64 + 32 + q * 8);
    short8 f00, f01, f10, f11;
    bool has2 = (e_s2 != nullptr);
    if (has2) {
        f00 = *(const short8*)(e_s2 + (size_t)pp0 * 64 + q * 8);
        f01 = *(const short8*)(e_s2 + (size_t)pp0 * 64 + 32 + q * 8);
        f10 = *(const short8*)(e_s2 + (size_t)pp1 * 64 + q * 8);
        f11 = *(const short8*)(e_s2 + (size_t)pp1 * 64 + 32 + q * 8);
    }

    if (ln_edge) {
        {   // tile0 edge LN (with optional fused residual add, f32)
            float ev[16];
            float sm = 0.f, sq = 0.f;
#pragma unroll
            for (int i = 0; i < 8; i++) {
                float f0 = bf2f((u16)e00[i]);
                float f1 = bf2f((u16)e01[i]);
                if (has2) { f0 += bf2f((u16)f00[i]); f1 += bf2f((u16)f01[i]); }
                ev[i] = f0; ev[8 + i] = f1;
                sm += f0 + f1; sq += f0 * f0 + f1 * f1;
            }
            sm += __shfl_xor(sm, 16); sm += __shfl_xor(sm, 32);
            sq += __shfl_xor(sq, 16); sq += __shfl_xor(sq, 32);
            float mu = sm * (1.f / 64.f);
            float var = sq * (1.f / 64.f) - mu * mu;
            float inv = rsqrtf(fmaxf(var, 0.f) + LN_EPS);
#pragma unroll
            for (int i = 0; i < 8; i++) {
                int c0 = q * 8 + i, c1 = 32 + q * 8 + i;
                a0[4][i] = (short)f2bf((ev[i] - mu) * inv * elng[c0] + elnb[c0]);
                a0[5][i] = (short)f2bf((ev[8 + i] - mu) * inv * elng[c1] + elnb[c1]);
            }
        }
        {   // tile1 edge LN
            float ev[16];
            float sm = 0.f, sq = 0.f;
#pragma unroll
            for (int i = 0; i < 8; i++) {
                float f0 = bf2f((u16)e10[i]);
                float f1 = bf2f((u16)e11[i]);
                if (has2) { f0 += bf2f((u16)f10[i]); f1 += bf2f((u16)f11[i]); }
                ev[i] = f0; ev[8 + i] = f1;
                sm += f0 + f1; sq += f0 * f0 + f1 * f1;
            }
            sm += __shfl_xor(sm, 16); sm += __shfl_xor(sm, 32);
            sq += __shfl_xor(sq, 16); sq += __shfl_xor(sq, 32);
            float mu = sm * (1.f / 64.f);
            float var = sq * (1.f / 64.f) - mu * mu;
            float inv = rsqrtf(fmaxf(var, 0.f) + LN_EPS);
#pragma unroll
            for (int i = 0; i < 8; i++) {
                int c0 = q * 8 + i, c1 = 32 + q * 8 + i;
                a1[4][i] = (short)f2bf((ev[i] - mu) * inv * elng[c0] + elnb[c0]);
                a1[5][i] = (short)f2bf((ev[8 + i] - mu) * inv * elng[c1] + elnb[c1]);
            }
        }
    } else {
        a0[4] = e00; a0[5] = e01;
        a1[4] = e10; a1[5] = e11;
    }

    __syncthreads();   // weights staged (DMA drained by barrier's vmcnt(0))

    floatx4 acc0[8], acc1[8];
#pragma unroll
    for (int nt = 0; nt < 8; nt++) {
        acc0[nt] = floatx4{0.f, 0.f, 0.f, 0.f};
        acc1[nt] = floatx4{0.f, 0.f, 0.f, 0.f};
    }
#pragma unroll
    for (int kt = 0; kt < 6; kt++) {
#pragma unroll
        for (int nt = 0; nt < 8; nt++) {
            short8 bf = *((const short8*)(sShared + ((kt * 4 + q) * 128 + nt * 16 + ml) * 8));
            acc0[nt] = __builtin_amdgcn_mfma_f32_16x16x32_bf16(a0[kt], bf, acc0[nt], 0, 0, 0);
            acc1[nt] = __builtin_amdgcn_mfma_f32_16x16x32_bf16(a1[kt], bf, acc1[nt], 0, 0, 0);
        }
    }

    __syncthreads();   // all waves done reading W1 frags; arenas may overlay

    // Bias loads deferred here to keep W1-loop live set under the VGPR cap.
    float b1c[8], b2c[4];
#pragma unroll
    for (int nt = 0; nt < 8; nt++) b1c[nt] = b1[nt * 16 + ml];
#pragma unroll
    for (int nt = 0; nt < 4; nt++) b2c[nt] = b2[nt * 16 + ml];

    short* arena = sShared + w * 16 * HSTR;

    // tile0 W1-out -> arena -> A-frags
#pragma unroll
    for (int nt = 0; nt < 8; nt++) {
#pragma unroll
        for (int r2 = 0; r2 < 4; r2++) {
            float v = fmaxf(acc0[nt][r2] + b1c[nt], 0.f);
            ((u16*)arena)[(q * 4 + r2) * HSTR + nt * 16 + ml] = f2bf(v);
        }
    }
    short8 ah0[4];
#pragma unroll
    for (int kt = 0; kt < 4; kt++)
        ah0[kt] = *((const short8*)(arena + ml * HSTR + kt * 32 + q * 8));

    // tile1 W1-out -> arena -> A-frags (same region; within-wave ordering via lgkmcnt)
#pragma unroll
    for (int nt = 0; nt < 8; nt++) {
#pragma unroll
        for (int r2 = 0; r2 < 4; r2++) {
            float v = fmaxf(acc1[nt][r2] + b1c[nt], 0.f);
            ((u16*)arena)[(q * 4 + r2) * HSTR + nt * 16 + ml] = f2bf(v);
        }
    }
    short8 ah1[4];
#pragma unroll
    for (int kt = 0; kt < 4; kt++)
        ah1[kt] = *((const short8*)(arena + ml * HSTR + kt * 32 + q * 8));

    // Shared W2 loop: one B-frag read feeds both tiles. (Last reader of sW2L.)
    floatx4 c20[4], c21[4];
#pragma unroll
    for (int nt = 0; nt < 4; nt++) {
        c20[nt] = floatx4{0.f, 0.f, 0.f, 0.f};
        c21[nt] = floatx4{0.f, 0.f, 0.f, 0.f};
    }
#pragma unroll
    for (int kt = 0; kt < 4; kt++) {
#pragma unroll
        for (int nt = 0; nt < 4; nt++) {
            short8 bf = *((const short8*)(sW2L + ((kt * 4 + q) * 64 + nt * 16 + ml) * 8));
            c20[nt] = __builtin_amdgcn_mfma_f32_16x16x32_bf16(ah0[kt], bf, c20[nt], 0, 0, 0);
            c21[nt] = __builtin_amdgcn_mfma_f32_16x16x32_bf16(ah1[kt], bf, c21[nt], 0, 0, 0);
        }
    }

    // tile0 output
#pragma unroll
    for (int nt = 0; nt < 4; nt++) {
#pragma unroll
        for (int r2 = 0; r2 < 4; r2++) {
            ((u16*)arena)[(q * 4 + r2) * HSTR + nt * 16 + ml] = f2bf(c20[nt][r2] + b2c[nt]);
        }
    }
    {
        short8 m0 = *((const short8*)(arena + ml * HSTR + q * 16));
        short8 m1 = *((const short8*)(arena + ml * HSTR + q * 16 + 8));
        if (act0) {
            *((short8*)(m_out + (size_t)pos0 * 64 + q * 16)) = m0;
            *((short8*)(m_out + (size_t)pos0 * 64 + q * 16 + 8)) = m1;
        }
    }
    // tile1 output
#pragma unroll
    for (int nt = 0; nt < 4; nt++) {
#pragma unroll
        for (int r2 = 0; r2 < 4; r2++) {
            ((u16*)arena)[(q * 4 + r2) * HSTR + nt * 16 + ml] = f2bf(c21[nt][r2] + b2c[nt]);
        }
    }
    {
        short8 m0 = *((const short8*)(arena + ml * HSTR + q * 16));
        short8 m1 = *((const short8*)(arena + ml * HSTR + q * 16 + 8));
        if (act1) {
            *((short8*)(m_out + (size_t)pos1 * 64 + q * 16)) = m0;
            *((short8*)(m_out + (size_t)pos1 * 64 + q * 16 + 8)) = m1;
        }
    }

    // ---- fused root (layers 1/2): h += hn @ Wr, exact k_root body ----
    if (do_root && blockIdx.x < ((nn + 127) >> 7)) {
        __syncthreads();   // all waves done reading sW2L
        int nbase = blockIdx.x * 128;
        {
            int r = t >> 2, s = t & 3;
            int pos = nbase + r;
            int g2 = r >> 4, mm = r & 15;
            short* grp = sW2L + g2 * 1024;
            bool ract = pos < nn;
            uint4 z4 = make_uint4(0, 0, 0, 0);
            const uint4* pd = (const uint4*)(hn + (size_t)(ract ? pos : 0) * 64);
            uint4 d0 = ract ? pd[2 * s] : z4;
            uint4 d1 = ract ? pd[2 * s + 1] : z4;
            int ch = (s >> 1) * 4 + (s & 1) * 2;
            *((uint4*)(grp + ch * 128 + mm * 8)) = d0;
            *((uint4*)(grp + (ch + 1) * 128 + mm * 8)) = d1;
        }
        __syncthreads();
        short* rA = sW2L + w * 1024;
        floatx4 racc[4];
#pragma unroll
        for (int nt = 0; nt < 4; nt++) racc[nt] = floatx4{0.f, 0.f, 0.f, 0.f};
#pragma unroll
        for (int kt = 0; kt < 2; kt++) {
            short8 aa = *((const short8*)(rA + (kt * 4 + q) * 128 + ml * 8));
#pragma unroll
            for (int nt = 0; nt < 4; nt++) {
                short8 bf = *((const short8*)(Wrs + (size_t)((kt * 4 + q) * 64 + nt * 16 + ml) * 8));
                racc[nt] = __builtin_amdgcn_mfma_f32_16x16x32_bf16(aa, bf, racc[nt], 0, 0, 0);
            }
        }
#pragma unroll
        for (int nt = 0; nt < 4; nt++) {
#pragma unroll
            for (int r2 = 0; r2 < 4; r2++) {
                int pos = nbase + w * 16 + q * 4 + r2;
                if (pos < nn) {
                    size_t idx = (size_t)pos * 64 + nt * 16 + ml;
                    h[idx] += racc[nt][r2];
                }
            }
        }
    }
}

// ---------------- aggregation (chunked softmax) + fused layernorm ----------------
__global__ __launch_bounds__(256) void k_agg2(
    const u16* __restrict__ m_s, float* __restrict__ h,
    const int* __restrict__ offs, const float* __restrict__ tptr, int tidx,
    const float* __restrict__ g, const float* __restrict__ b,
    u16* __restrict__ hn_out, float* __restrict__ f32_out,
    int write_h, int n, int E) {
    int t = threadIdx.x, wid = t >> 6, lane = t & 63;
    float tv = tptr[tidx];
    float gc = g[lane], bc = b[lane];
    for (int node = blockIdx.x * 4 + wid; node < n; node += gridDim.x * 4) {
        int p0 = clampi(offs[node], 0, E);
        int p1 = clampi(offs[node + 1], p0, E);
        float hv = h[(size_t)node * 64 + lane];   // issued early, independent
        float M = -1e30f, D = 0.f, S = 0.f;
        for (int p = p0; p < p1; p += 8) {
            int cnt = p1 - p;
            float mv[8], lg[8];
#pragma unroll
            for (int j = 0; j < 8; j++) {
                int idx = (j < cnt) ? (p + j) : (p1 - 1);
                mv[j] = bf2f(m_s[(size_t)idx * 64 + lane]);
                lg[j] = (j < cnt) ? mv[j] * tv : -1e30f;
            }
            float Mc = fmaxf(fmaxf(fmaxf(lg[0], lg[1]), fmaxf(lg[2], lg[3])),
                             fmaxf(fmaxf(lg[4], lg[5]), fmaxf(lg[6], lg[7])));
            float e0 = __expf(lg[0] - Mc), e1 = __expf(lg[1] - Mc);
            float e2 = __expf(lg[2] - Mc), e3 = __expf(lg[3] - Mc);
            float e4 = __expf(lg[4] - Mc), e5 = __expf(lg[5] - Mc);
            float e6 = __expf(lg[6] - Mc), e7 = __expf(lg[7] - Mc);
            float Dc = ((e0 + e1) + (e2 + e3)) + ((e4 + e5) + (e6 + e7));
            float Sc = ((mv[0] * e0 + mv[1] * e1) + (mv[2] * e2 + mv[3] * e3)) +
                       ((mv[4] * e4 + mv[5] * e5) + (mv[6] * e6 + mv[7] * e7));
            float Mn = fmaxf(M, Mc);
            float xa = __expf(M - Mn), xb = __expf(Mc - Mn);
            D = D * xa + Dc * xb;
            S = S * xa + Sc * xb;
            M = Mn;
        }
        if (p1 > p0) hv += S / D;
        if (write_h) h[(size_t)node * 64 + lane] = hv;
        // fused layernorm + relu
        float s = hv;
#pragma unroll
        for (int o = 32; o > 0; o >>= 1) s += __shfl_xor(s, o);
        float mu = s * (1.f / 64.f);
        float d = hv - mu;
        float s2 = d * d;
#pragma unroll
        for (int o = 32; o > 0; o >>= 1) s2 += __shfl_xor(s2, o);
        float inv = rsqrtf(s2 * (1.f / 64.f) + LN_EPS);
        float r = fmaxf(d * inv * gc + bc, 0.f);
        if (hn_out) hn_out[(size_t)node * 64 + lane] = f2bf(r);
        else        f32_out[(size_t)node * 64 + lane] = r;
    }
}

// ---------------- launcher ----------------
extern "C" void kernel_launch(void* const* d_in, const int* in_sizes, int n_in,
                              void* d_out, int out_size, void* d_ws, size_t ws_size,
                              hipStream_t stream) {
    float* outp = (float*)d_out;
    int FB = (out_size + 255) / 256;

    if (n_in != 17) {
        k_fill<<<FB, 256, 0, stream>>>(outp, out_size, 3.0f);
        return;
    }

    const float* x    = (const float*)d_in[0];
    const int*   ei   = (const int*)d_in[1];
    const float* ea   = (const float*)d_in[2];
    const float* nW   = (const float*)d_in[3];
    const float* nb   = (const float*)d_in[4];
    const float* eW   = (const float*)d_in[5];
    const float* eb   = (const float*)d_in[6];
    const float* cW1  = (const float*)d_in[7];
    const float* cb1  = (const float*)d_in[8];
    const float* cW2  = (const float*)d_in[9];
    const float* cb2  = (const float*)d_in[10];
    const float* cWr  = (const float*)d_in[11];
    const float* ct   = (const float*)d_in[12];
    const float* lng  = (const float*)d_in[13];
    const float* lnb  = (const float*)d_in[14];
    const float* elng = (const float*)d_in[15];
    const float* elnb = (const float*)d_in[16];

    const int n = in_sizes[0] / 128;   // 50000
    const int E = in_sizes[2] / 16;    // 500000

    char* ws = (char*)d_ws;
    size_t o = 0;
    auto alloc = [&](size_t bytes) -> void* {
        void* p = ws + o;
        o += (bytes + 255) & ~(size_t)255;
        return p;
    };
    int*   flag   = (int*)alloc(256);
    int*   deg    = (int*)alloc((size_t)n * 4);
    int*   offs   = (int*)alloc((size_t)(n + 1) * 4);
    int*   cursor = (int*)alloc((size_t)n * 4);
    int*   bsum   = (int*)alloc(256 * 4);
    int*   perm   = (int*)alloc((size_t)E * 4);
    int*   srcs   = (int*)alloc((size_t)E * 4);
    int*   dsts   = (int*)alloc((size_t)E * 4);
    float* h      = (float*)alloc((size_t)n * 64 * 4);
    u16*   hn     = (u16*)alloc((size_t)n * 64 * 2);
    u16*   bufA   = (u16*)alloc((size_t)E * 64 * 2);
    u16*   bufB   = (u16*)alloc((size_t)E * 64 * 2);
    u16*   W1s    = (u16*)alloc((size_t)3 * 24576 * 2);
    u16*   W2s    = (u16*)alloc((size_t)3 * 8192 * 2);
    u16*   Wrs    = (u16*)alloc((size_t)3 * 4096 * 2);
    u16*   nWs    = (u16*)alloc((size_t)8192 * 2);

    if (o > ws_size) {
        k_fill<<<FB, 256, 0, stream>>>(outp, out_size, 2.0f);
        return;
    }

    int SB = (n + 255) / 256;
    int PB = (3 * 24576 + 255) / 256;   // 288 >= SB for n=50000
    if (SB > PB) PB = SB;
    k_pre0<<<PB, 256, 0, stream>>>(ei, E, flag, deg, n,
                                   cW1, cW2, cWr, nW, W1s, W2s, Wrs, nWs);
    k_hist<<<(E + 255) / 256, 256, 0, stream>>>(ei, flag, deg, E, n);
    k_scan1<<<SB, 256, 0, stream>>>(deg, offs, bsum, n);
    k_scan23<<<SB, 256, 0, stream>>>(offs, bsum, cursor, n, E, SB);
    k_scatter<<<(E + 255) / 256, 256, 0, stream>>>(ei, flag, cursor, perm, srcs, dsts, E, n);

    int RB = (n + 127) / 128;
    int EB2 = (E * 4 + 511) / 512;
    k_enc<<<RB + EB2, 512, 0, stream>>>(x, nWs, nb, Wrs, h, hn, n,
                                        ea, perm, eW, eb, bufA, E, RB);

    // Buffer schedule (ping-pong, no copies):
    //  L0: mlp(in=bufA)            -> bufB(m1); agg: LN->hn(lng[1])  [root0 in k_enc]
    //  L1: mlp(in=bufB, root Wr1)  -> bufA(m2); agg: LN->hn(lng[2])
    //  L2: mlp(in=bufB,in2=bufA, root Wr2) -> bufA(m3); agg: LN->out(lng[0])
    int MB = (E + TILE - 1) / TILE;
    int AB = (n + 3) / 4;

    const u16* mlp_in[3]  = { bufA, bufB, bufB };
    const u16* mlp_in2[3] = { nullptr, nullptr, bufA };
    u16*       mlp_out[3] = { bufB, bufA, bufA };

    for (int i = 0; i < 3; i++) {
        k_mlp<<<MB, 512, 0, stream>>>(
            hn, mlp_in[i], mlp_in2[i], dsts, srcs,
            W1s + (size_t)i * 24576, cb1 + (size_t)i * 128,
            W2s + (size_t)i * 8192, cb2 + (size_t)i * 64,
            elng + (size_t)((i > 0) ? (i - 1) : 0) * 64,
            elnb + (size_t)((i > 0) ? (i - 1) : 0) * 64,
            (i > 0) ? 1 : 0, mlp_out[i], E,
            Wrs + (size_t)i * 4096, h, (i > 0) ? 1 : 0, n);
        if (i < 2) {
            k_agg2<<<AB, 256, 0, stream>>>(mlp_out[i], h, offs, ct, i,
                                           lng + (size_t)(i + 1) * 64, lnb + (size_t)(i + 1) * 64,
                                           hn, nullptr, 1, n, E);
        } else {
            k_agg2<<<AB, 256, 0, stream>>>(mlp_out[i], h, offs, ct, i,
                                           lng, lnb,
                                           nullptr, outp, 0, n, E);
        }
    }
}